// Round 9
// baseline (1116.717 us; speedup 1.0000x reference)
//
#include <hip/hip_runtime.h>
#include <hip/hip_bf16.h>
#include <math.h>

#define BDIM 16384
#define HDIM 512

typedef __bf16 bf16;
typedef float f32x4 __attribute__((ext_vector_type(4)));
typedef __bf16 bf16x8 __attribute__((ext_vector_type(8)));
typedef __bf16 bf16x4 __attribute__((ext_vector_type(4)));

#define WAITV(N) asm volatile("s_waitcnt vmcnt(" #N ")" ::: "memory")

// ---------------------------------------------------------------- utilities

__device__ __forceinline__ void gload16(const bf16* g, bf16* l) {
  __builtin_amdgcn_global_load_lds((const __attribute__((address_space(1))) void*)g,
                                   (__attribute__((address_space(3))) void*)l, 16, 0, 0);
}
__device__ __forceinline__ void gload4(const bf16* g, bf16* l) {
  __builtin_amdgcn_global_load_lds((const __attribute__((address_space(1))) void*)g,
                                   (__attribute__((address_space(3))) void*)l, 4, 0, 0);
}

__device__ __forceinline__ float gelu_exact(float x) {
  return 0.5f * x * (1.0f + erff(x * 0.70710678118654752f));
}
// gelu(x) ~= x * sigmoid(2*0.7978845608*(x + 0.044715 x^3)); exp2-form, rcp.
__device__ __forceinline__ float gelu_fast2(float x) {
  float x3 = x * x * x;
  float e = exp2f(fmaf(-0.1029432f, x3, -2.3022082f * x));
  return x * __builtin_amdgcn_rcpf(1.f + e);
}

// ---------------------------------------------------------------- converts

__global__ void cvt_f32_bf16(const float* __restrict__ src, bf16* __restrict__ dst, int n4) {
  int i = blockIdx.x * blockDim.x + threadIdx.x;
  if (i >= n4) return;
  f32x4 v = *(const f32x4*)(src + (size_t)i * 4);
  bf16x4 o;
  o[0] = (bf16)v[0]; o[1] = (bf16)v[1]; o[2] = (bf16)v[2]; o[3] = (bf16)v[3];
  *(bf16x4*)(dst + (size_t)i * 4) = o;
}

// wvT[il][k][m] = wv[il][m][k]; wv = rows 1024..1535 of qkv block il ([1536][512])
__global__ void cvt_wvT(const float* __restrict__ qkv, bf16* __restrict__ dst) {
  __shared__ float t[32][33];
  int il = blockIdx.z;
  int bm = blockIdx.x * 32;
  int bk = blockIdx.y * 32;
  const float* s = qkv + (size_t)il * 786432 + 524288;
  int tx = threadIdx.x & 31, ty = threadIdx.x >> 5;
#pragma unroll
  for (int j = 0; j < 4; ++j)
    t[ty * 4 + j][tx] = s[(size_t)(bm + ty * 4 + j) * 512 + bk + tx];
  __syncthreads();
  bf16* d = dst + (size_t)il * 262144;
#pragma unroll
  for (int j = 0; j < 4; ++j)
    d[(size_t)(bk + ty * 4 + j) * 512 + bm + tx] = (bf16)t[tx][ty * 4 + j];
}

__global__ void zfill(float* __restrict__ p, int n) {
  int i = blockIdx.x * 256 + threadIdx.x;
  if (i < n) p[i] = 0.f;
}

// bc[il][n] = sum_m ao[il][n][m] * bv[il][m] + aob[il][n]
__global__ void bias_combine(const float* __restrict__ aow, const float* __restrict__ qkvb,
                             const float* __restrict__ aob, float* __restrict__ bc) {
  int gid = blockIdx.x * 4 + (threadIdx.x >> 6);
  int il = gid >> 9;
  int lane = threadIdx.x & 63;
  const float* ar = aow + (size_t)gid * 512 + lane * 8;
  const float* bv = qkvb + il * 1536 + 1024 + lane * 8;
  float s = 0.f;
#pragma unroll
  for (int i = 0; i < 8; ++i) s += ar[i] * bv[i];
#pragma unroll
  for (int off = 32; off > 0; off >>= 1) s += __shfl_xor(s, off);
  if (lane == 0) bc[gid] = s + aob[gid];
}

// ---------------------------------------------------------------- gemm_q (attn/ip/op)
// 128x256 tile, BK=32, 4 waves, 3-slot ring, counted vmcnt, swizzle, setprio.
// Swapped mfma(b,a): row=m*16+lr, cols=bcol+wn+n*16+kg*4 (bf16x4 stores).

template<int ACT, bool RES, int K>
__launch_bounds__(256, 2)
__global__ void gemm_q(const bf16* __restrict__ A, long long Az,
                       const bf16* __restrict__ W, long long Wz,
                       const float* __restrict__ bias, long long bz,
                       const bf16* X, long long Xz,
                       bf16* C, long long Cz, int ldc) {
  __shared__ bf16 lds[3][12288];
  const long long z = blockIdx.z;
  A += z * Az; W += z * Wz; bias += z * bz; C += z * Cz;
  if (RES) X += z * Xz;
  const int tid = threadIdx.x, lane = tid & 63, wid = tid >> 6;
  const int brow = blockIdx.x * 128, bcol = blockIdx.y * 256;
  const int wn = wid * 64, lr = lane & 15, kg = lane >> 4;
  const int ko = (kg ^ ((lr >> 1) & 3)) << 3;

  f32x4 acc[8][4] = {};

  const int sco = (((tid & 3) ^ ((tid >> 3) & 3)) << 3);
  const bf16* Ag = A + (size_t)(brow + (tid >> 2)) * K + sco;
  const bf16* Wg = W + (size_t)(bcol + (tid >> 2)) * K + sco;
  auto SA = [&](int s, int kt, int u) {
    gload16(Ag + (size_t)u * 64 * K + kt * 32, &lds[s][u * 2048 + wid * 512]);
  };
  auto SB = [&](int s, int kt, int u) {
    gload16(Wg + (size_t)u * 64 * K + kt * 32, &lds[s][4096 + u * 2048 + wid * 512]);
  };

  const int nt = K / 32;
  SA(0,0,0); SA(0,0,1); SB(0,0,0); SB(0,0,1); SB(0,0,2); SB(0,0,3);
  SA(1,1,0); SA(1,1,1); SB(1,1,0); SB(1,1,1); SB(1,1,2); SB(1,1,3);

  int slot = 0;
  for (int t = 0; t < nt; ++t) {
    int s2 = slot + 2; if (s2 >= 3) s2 -= 3;
    const bf16* LA = &lds[slot][0];
    const bf16* LB = &lds[slot][4096];
    if (t + 2 < nt) { SA(s2,t+2,0); SA(s2,t+2,1); SB(s2,t+2,0); SB(s2,t+2,1); }
    if (t + 2 < nt)      WAITV(10);
    else if (t + 1 < nt) WAITV(6);
    else                 WAITV(0);
    __builtin_amdgcn_s_barrier();
    bf16x8 a[8], b0, b1;
#pragma unroll
    for (int m = 0; m < 8; ++m) a[m] = *(const bf16x8*)(LA + ((m*16+lr)<<5) + ko);
    b0 = *(const bf16x8*)(LB + ((wn + lr)<<5) + ko);
    b1 = *(const bf16x8*)(LB + ((wn + 16 + lr)<<5) + ko);
    __builtin_amdgcn_s_setprio(1);
#pragma unroll
    for (int m = 0; m < 8; ++m) {
      acc[m][0] = __builtin_amdgcn_mfma_f32_16x16x32_bf16(b0, a[m], acc[m][0], 0, 0, 0);
      acc[m][1] = __builtin_amdgcn_mfma_f32_16x16x32_bf16(b1, a[m], acc[m][1], 0, 0, 0);
    }
    __builtin_amdgcn_s_setprio(0);
    asm volatile("" ::: "memory");
    __builtin_amdgcn_s_barrier();
    if (t + 2 < nt) { SB(s2,t+2,2); SB(s2,t+2,3); }
    bf16x8 b2 = *(const bf16x8*)(LB + ((wn + 32 + lr)<<5) + ko);
    bf16x8 b3 = *(const bf16x8*)(LB + ((wn + 48 + lr)<<5) + ko);
    __builtin_amdgcn_s_setprio(1);
#pragma unroll
    for (int m = 0; m < 8; ++m) {
      acc[m][2] = __builtin_amdgcn_mfma_f32_16x16x32_bf16(b2, a[m], acc[m][2], 0, 0, 0);
      acc[m][3] = __builtin_amdgcn_mfma_f32_16x16x32_bf16(b3, a[m], acc[m][3], 0, 0, 0);
    }
    __builtin_amdgcn_s_setprio(0);
    asm volatile("" ::: "memory");
    __builtin_amdgcn_s_barrier();
    slot += 1; if (slot >= 3) slot = 0;
  }

  f32x4 bv4[4];
#pragma unroll
  for (int n = 0; n < 4; ++n)
    bv4[n] = *(const f32x4*)(bias + bcol + wn + n * 16 + kg * 4);
#pragma unroll
  for (int m = 0; m < 8; ++m) {
    int row = brow + m * 16 + lr;
#pragma unroll
    for (int n = 0; n < 4; ++n) {
      int col = bcol + wn + n * 16 + kg * 4;
      f32x4 v;
#pragma unroll
      for (int j = 0; j < 4; ++j) {
        float t = acc[m][n][j] + bv4[n][j];
        if (ACT == 1) t = gelu_fast2(t);
        v[j] = t;
      }
      if (RES) {
        bf16x4 xv = *(const bf16x4*)(X + (size_t)row * 512 + col);
#pragma unroll
        for (int j = 0; j < 4; ++j) v[j] += (float)xv[j];
      }
      bf16x4 o;
#pragma unroll
      for (int j = 0; j < 4; ++j) o[j] = (bf16)v[j];
      *(bf16x4*)(C + (size_t)row * ldc + col) = o;
    }
  }
}

// ---------------------------------------------------------------- gemm_mlp (fused FFN)
// O = X + gelu(X @ W1^T + b1) @ W2^T + b2.  X:[B][512], W1:[2048][512], W2:[512][2048].
// BM=64, 8 waves, h in LDS only. 16 chunks of 128 h-cols:
//   GEMM1 (16 ksteps BK=32, A/W1 ring3 dist2) -> gelu -> h LDS -> GEMM2 (4 ksteps, W2 ring2).
// Uniform 3 loads/kstep -> hand-derived vmcnt ledger. b1 cached in LDS (no vmcnt pollution).

__launch_bounds__(512, 2)
__global__ void gemm_mlp(const bf16* __restrict__ Xg, long long Xz,
                         const bf16* __restrict__ W1g, long long W1z,
                         const float* __restrict__ b1g, long long b1z,
                         const bf16* __restrict__ W2g, long long W2z,
                         const float* __restrict__ b2g, long long b2z,
                         bf16* O, long long Oz) {
  __shared__ bf16 lds[63488];   // 124 KiB
  const long long z = blockIdx.z;
  const bf16* X = Xg + z * Xz;
  W1g += z * W1z; b1g += z * b1z; W2g += z * W2z; b2g += z * b2z; O += z * Oz;

  const int tid = threadIdx.x, lane = tid & 63, wid = tid >> 6;
  const int brow = blockIdx.x * 64;
  const int lr = lane & 15, kg = lane >> 4;
  const int ko = (kg ^ ((lr >> 1) & 3)) << 3;

  constexpr int AR  = 0;       // 3 x [64][32]  = 3*2048
  constexpr int W1R = 6144;    // 3 x [128][32] = 3*4096
  constexpr int HB  = 18432;   // 4 x [64][32]  = 8192
  constexpr int W2R = 26624;   // 2 x [512][32] = 2*16384
  float* B1 = (float*)(lds + 59392);   // 2048 f32

  // b1 -> LDS (completes before any async staging wait matters)
  {
    f32x4 bv = *(const f32x4*)(b1g + tid * 4);
    *(f32x4*)(B1 + tid * 4) = bv;
  }

  const int sco16 = (((tid & 3) ^ ((tid >> 3) & 3)) << 3);
  const int scoA  = ((((tid >> 2) & 3) ^ ((tid >> 5) & 3)) << 3) + ((tid & 3) << 1);
  const bf16* Ag0 = X + (size_t)(brow + (tid >> 4)) * 512 + scoA;
  const bf16* Ag1 = Ag0 + (size_t)32 * 512;
  const bf16* W1c = W1g + (size_t)(tid >> 2) * 512 + sco16;   // +65536 per chunk
  const bf16* W2c = W2g + (size_t)(tid >> 2) * 2048 + sco16;  // +128 per chunk

  auto SA = [&](int sl, int ks) {
    gload4(Ag0 + ks * 32, lds + AR + sl * 2048 + wid * 128);
    gload4(Ag1 + ks * 32, lds + AR + sl * 2048 + 1024 + wid * 128);
  };
  auto SW1 = [&](int sl, int ks, const bf16* w1p) {
    gload16(w1p + ks * 32, lds + W1R + sl * 4096 + wid * 512);
  };
  auto SW2 = [&](int sl, int j, const bf16* w2p) {
#pragma unroll
    for (int u = 0; u < 4; ++u)
      gload16(w2p + (size_t)u * 128 * 2048 + j * 32,
              lds + W2R + sl * 16384 + u * 4096 + wid * 512);
  };

  f32x4 acc2[4][4] = {};

  // prologue: chunk0 tiles 0,1
  SA(0, 0); SW1(0, 0, W1c);
  SA(1, 1); SW1(1, 1, W1c);
  __syncthreads();

  int sb = 0;
  for (int c = 0; c < 16; ++c) {
    const bf16* W1n = W1c + 65536;
    f32x4 acc1[4] = {};

    // ---------------- GEMM1 ----------------
#pragma unroll
    for (int ks = 0; ks < 16; ++ks) {
      int sl = ks % 3 + sb;       if (sl >= 3) sl -= 3;
      int s2 = (ks + 2) % 3 + sb; if (s2 >= 3) s2 -= 3;
      if (ks < 14) { SA(s2, ks + 2); SW1(s2, ks + 2, W1c); }
      if (ks == 8)  SW2(0, 0, W2c);
      if (ks == 10) SW2(1, 1, W2c);
      if (ks < 8 || ks == 13)  WAITV(6);
      else if (ks == 10)       WAITV(14);
      else if (ks == 14)       WAITV(3);
      else if (ks == 15)       WAITV(0);
      else                     WAITV(10);   // ks = 8,9,11,12
      __builtin_amdgcn_s_barrier();
      bf16x8 b1f = *(const bf16x8*)(lds + W1R + sl * 4096 + ((wid * 16 + lr) << 5) + ko);
      bf16x8 a0 = *(const bf16x8*)(lds + AR + sl * 2048 + ((lr) << 5) + ko);
      bf16x8 a1 = *(const bf16x8*)(lds + AR + sl * 2048 + ((16 + lr) << 5) + ko);
      bf16x8 a2 = *(const bf16x8*)(lds + AR + sl * 2048 + ((32 + lr) << 5) + ko);
      bf16x8 a3 = *(const bf16x8*)(lds + AR + sl * 2048 + ((48 + lr) << 5) + ko);
      __builtin_amdgcn_s_setprio(1);
      acc1[0] = __builtin_amdgcn_mfma_f32_16x16x32_bf16(b1f, a0, acc1[0], 0, 0, 0);
      acc1[1] = __builtin_amdgcn_mfma_f32_16x16x32_bf16(b1f, a1, acc1[1], 0, 0, 0);
      acc1[2] = __builtin_amdgcn_mfma_f32_16x16x32_bf16(b1f, a2, acc1[2], 0, 0, 0);
      acc1[3] = __builtin_amdgcn_mfma_f32_16x16x32_bf16(b1f, a3, acc1[3], 0, 0, 0);
      __builtin_amdgcn_s_setprio(0);
      asm volatile("" ::: "memory");
      __builtin_amdgcn_s_barrier();
    }

    // ---------------- h phase ----------------
    {
      f32x4 b1v = *(const f32x4*)(B1 + c * 128 + wid * 16 + kg * 4);
      int colb = wid * 16 + kg * 4;
      int hw = HB + ((colb >> 5) * 2048)
             + ((((colb >> 3) & 3) ^ ((lr >> 1) & 3)) << 3) + (colb & 7);
#pragma unroll
      for (int m = 0; m < 4; ++m) {
        bf16x4 hv;
#pragma unroll
        for (int j = 0; j < 4; ++j) hv[j] = (bf16)gelu_fast2(acc1[m][j] + b1v[j]);
        *(bf16x4*)(lds + hw + ((m * 16 + lr) << 5)) = hv;
      }
    }
    __syncthreads();

    // ---------------- GEMM2 ----------------
    int sbn = sb + 1;  if (sbn >= 3) sbn -= 3;
    int sb2 = sbn + 1; if (sb2 >= 3) sb2 -= 3;
    const bool more = (c + 1 < 16);
#pragma unroll
    for (int j = 0; j < 4; ++j) {
      if (j == 2) {
        if (more) { SA(sb2, 1); SW1(sb2, 1, W1n); }
        if (more) WAITV(10); else WAITV(4);
        __builtin_amdgcn_s_barrier();
      } else if (j == 3) {
        if (more) WAITV(6); else WAITV(0);
        __builtin_amdgcn_s_barrier();
      }
      bf16x8 bw0 = *(const bf16x8*)(lds + W2R + (j & 1) * 16384 + ((wid * 64 + lr) << 5) + ko);
      bf16x8 bw1 = *(const bf16x8*)(lds + W2R + (j & 1) * 16384 + ((wid * 64 + 16 + lr) << 5) + ko);
      bf16x8 bw2 = *(const bf16x8*)(lds + W2R + (j & 1) * 16384 + ((wid * 64 + 32 + lr) << 5) + ko);
      bf16x8 bw3 = *(const bf16x8*)(lds + W2R + (j & 1) * 16384 + ((wid * 64 + 48 + lr) << 5) + ko);
      bf16x8 ah[4];
#pragma unroll
      for (int m = 0; m < 4; ++m)
        ah[m] = *(const bf16x8*)(lds + HB + j * 2048 + ((m * 16 + lr) << 5) + ko);
      __builtin_amdgcn_s_setprio(1);
#pragma unroll
      for (int m = 0; m < 4; ++m) {
        acc2[m][0] = __builtin_amdgcn_mfma_f32_16x16x32_bf16(bw0, ah[m], acc2[m][0], 0, 0, 0);
        acc2[m][1] = __builtin_amdgcn_mfma_f32_16x16x32_bf16(bw1, ah[m], acc2[m][1], 0, 0, 0);
        acc2[m][2] = __builtin_amdgcn_mfma_f32_16x16x32_bf16(bw2, ah[m], acc2[m][2], 0, 0, 0);
        acc2[m][3] = __builtin_amdgcn_mfma_f32_16x16x32_bf16(bw3, ah[m], acc2[m][3], 0, 0, 0);
      }
      __builtin_amdgcn_s_setprio(0);
      asm volatile("" ::: "memory");
      __builtin_amdgcn_s_barrier();
      if (j == 0) { SW2(0, 2, W2c); }
      if (j == 1) { SW2(1, 3, W2c); if (more) { SA(sbn, 0); SW1(sbn, 0, W1n); } }
    }

    W1c = W1n;
    W2c += 128;
    sb = sbn;
  }

  // ---------------- epilogue: +b2 +X -> O ----------------
  f32x4 b2v[4];
#pragma unroll
  for (int n = 0; n < 4; ++n)
    b2v[n] = *(const f32x4*)(b2g + wid * 64 + n * 16 + kg * 4);
#pragma unroll
  for (int m = 0; m < 4; ++m) {
    int row = brow + m * 16 + lr;
#pragma unroll
    for (int n = 0; n < 4; ++n) {
      int col = wid * 64 + n * 16 + kg * 4;
      bf16x4 xv = *(const bf16x4*)(X + (size_t)row * 512 + col);
      bf16x4 o;
#pragma unroll
      for (int j = 0; j < 4; ++j)
        o[j] = (bf16)(acc2[m][n][j] + b2v[n][j] + (float)xv[j]);
      *(bf16x4*)(O + (size_t)row * 512 + col) = o;
    }
  }
}

// ---------------------------------------------------------------- ln_chain
// MODE 0: O = LN_A(Y);  MODE 1: O = LN_B( LN_A(Y) + R )

template<int MODE>
__global__ void ln_chain(const bf16* __restrict__ Y, const bf16* __restrict__ R,
                         const float* __restrict__ gA, const float* __restrict__ bA,
                         const float* __restrict__ gB, const float* __restrict__ bB,
                         bf16* __restrict__ O) {
  int lane = threadIdx.x & 63;
  int row = blockIdx.x * 4 + (threadIdx.x >> 6);
  int gen = row >> 14;
  size_t base = (size_t)row * HDIM + lane * 8;
  bf16x8 yv = *(const bf16x8*)(Y + base);
  float v[8], s = 0.f, q = 0.f;
#pragma unroll
  for (int i = 0; i < 8; ++i) { v[i] = (float)yv[i]; s += v[i]; q += v[i] * v[i]; }
#pragma unroll
  for (int off = 32; off > 0; off >>= 1) { s += __shfl_xor(s, off); q += __shfl_xor(q, off); }
  float mean = s * (1.f / HDIM);
  float rstd = rsqrtf(q * (1.f / HDIM) - mean * mean + 1e-5f);
  const float* gAp = gA + gen * 1536 + lane * 8;
  const float* bAp = bA + gen * 1536 + lane * 8;
  if (MODE == 0) {
    bf16x8 o;
#pragma unroll
    for (int i = 0; i < 8; ++i) o[i] = (bf16)((v[i] - mean) * rstd * gAp[i] + bAp[i]);
    *(bf16x8*)(O + base) = o;
    return;
  }
  bf16x8 rv = *(const bf16x8*)(R + base);
  float u[8]; s = 0.f; q = 0.f;
#pragma unroll
  for (int i = 0; i < 8; ++i) {
    u[i] = (v[i] - mean) * rstd * gAp[i] + bAp[i] + (float)rv[i];
    s += u[i]; q += u[i] * u[i];
  }
#pragma unroll
  for (int off = 32; off > 0; off >>= 1) { s += __shfl_xor(s, off); q += __shfl_xor(q, off); }
  float m2 = s * (1.f / HDIM);
  float r2 = rsqrtf(q * (1.f / HDIM) - m2 * m2 + 1e-5f);
  const float* gBp = gB + gen * 1536 + lane * 8;
  const float* bBp = bB + gen * 1536 + lane * 8;
  bf16x8 o;
#pragma unroll
  for (int i = 0; i < 8; ++i) o[i] = (bf16)((u[i] - m2) * r2 * gBp[i] + bBp[i]);
  *(bf16x8*)(O + base) = o;
}

// ---------------------------------------------------------------- GEMM 128x128 (tiny: Wc)

__launch_bounds__(256)
__global__ void gemm128(const bf16* __restrict__ A, long long Az, int lda,
                        const bf16* __restrict__ W, long long Wz,
                        const float* __restrict__ bias, long long bz,
                        bf16* __restrict__ C, long long Cz, int ldc, int K) {
  __shared__ bf16 As[128 * 64];
  __shared__ bf16 Bs[128 * 64];
  const long long z = blockIdx.z;
  A += z * Az; W += z * Wz; bias += z * bz; C += z * Cz;
  const int tid = threadIdx.x;
  const int lane = tid & 63;
  const int wid = tid >> 6;
  const int brow = blockIdx.x * 128;
  const int bcol = blockIdx.y * 128;
  const int wr = (wid >> 1) * 64;
  const int wc = (wid & 1) * 64;
  const int lr = lane & 15;
  const int kg = lane >> 4;
  f32x4 acc[4][4] = {};
  const bf16* Abase = A + (size_t)(brow + (tid >> 3)) * lda + ((tid & 7) << 3);
  const bf16* Wbase = W + (size_t)(bcol + (tid >> 3)) * K + ((tid & 7) << 3);
  bf16* AsDst = As + wid * 512;
  bf16* BsDst = Bs + wid * 512;
  for (int k0 = 0; k0 < K; k0 += 64) {
#pragma unroll
    for (int j = 0; j < 4; ++j) {
      gload16(Abase + (size_t)j * 32 * lda + k0, AsDst + j * 2048);
      gload16(Wbase + (size_t)j * 32 * K + k0, BsDst + j * 2048);
    }
    __syncthreads();
#pragma unroll
    for (int kk = 0; kk < 64; kk += 32) {
      bf16x8 a[4], bq[4];
#pragma unroll
      for (int m = 0; m < 4; ++m)
        a[m] = *(const bf16x8*)(As + (wr + m * 16 + lr) * 64 + kk + kg * 8);
#pragma unroll
      for (int n = 0; n < 4; ++n)
        bq[n] = *(const bf16x8*)(Bs + (wc + n * 16 + lr) * 64 + kk + kg * 8);
#pragma unroll
      for (int m = 0; m < 4; ++m)
#pragma unroll
        for (int n = 0; n < 4; ++n)
          acc[m][n] = __builtin_amdgcn_mfma_f32_16x16x32_bf16(a[m], bq[n], acc[m][n], 0, 0, 0);
    }
    __syncthreads();
  }
  float bv[4];
#pragma unroll
  for (int n = 0; n < 4; ++n) bv[n] = bias[bcol + wc + n * 16 + lr];
#pragma unroll
  for (int m = 0; m < 4; ++m) {
    int row = brow + wr + m * 16 + kg * 4;
#pragma unroll
    for (int n = 0; n < 4; ++n) {
      int col = bcol + wc + n * 16 + lr;
#pragma unroll
      for (int j = 0; j < 4; ++j)
        C[(size_t)(row + j) * ldc + col] = (bf16)(acc[m][n][j] + bv[n]);
    }
  }
}

// ---------------------------------------------------------------- prior MLP (tiny)

__global__ void prior_fc1(const float* __restrict__ emb, const float* __restrict__ w1,
                          const float* __restrict__ b1, float* __restrict__ h) {
  int j = blockIdx.x * 4 + (threadIdx.x >> 6);
  int lane = threadIdx.x & 63;
  const float* wr = w1 + (size_t)j * 512 + lane * 8;
  const float* e = emb + lane * 8;
  float s = 0.f;
#pragma unroll
  for (int i = 0; i < 8; ++i) s += e[i] * wr[i];
#pragma unroll
  for (int off = 32; off > 0; off >>= 1) s += __shfl_xor(s, off);
  if (lane == 0) h[j] = gelu_exact(s + b1[j]);
}

__global__ void prior_fc2(const float* __restrict__ h, const float* __restrict__ w2,
                          const float* __restrict__ b2, float* __restrict__ p) {
  int j = blockIdx.x * 4 + (threadIdx.x >> 6);
  int lane = threadIdx.x & 63;
  const float* wr = w2 + (size_t)j * 1024 + lane * 16;
  const float* e = h + lane * 16;
  float s = 0.f;
#pragma unroll
  for (int i = 0; i < 16; ++i) s += e[i] * wr[i];
#pragma unroll
  for (int off = 32; off > 0; off >>= 1) s += __shfl_xor(s, off);
  if (lane == 0) p[j] = s + b2[j];
}

// ---------------------------------------------------------------- final select/blend

__global__ void combine(const float* __restrict__ img, const float* __restrict__ txt,
                        const bf16* __restrict__ gen_t, const bf16* __restrict__ gen_i,
                        const float* __restrict__ prior, const int* __restrict__ mt,
                        const float* __restrict__ rw, float* __restrict__ out) {
  int i4 = blockIdx.x * blockDim.x + threadIdx.x;
  if (i4 >= BDIM * 128) return;
  int bb = i4 >> 7;
  int c = (i4 & 127) << 2;
  size_t idx = (size_t)bb * HDIM + c;
  int m = mt[bb];
  f32x4 iv = *(const f32x4*)(img + idx);
  f32x4 tv = *(const f32x4*)(txt + idx);
  f32x4 oi = iv, ot = tv;
  if (m == 2) {
    float r = rw[1];
    bf16x4 gv = *(const bf16x4*)(gen_i + idx);
#pragma unroll
    for (int k = 0; k < 4; ++k) oi[k] = r * iv[k] + (1.f - r) * (float)gv[k];
  } else if (m == 3) {
    oi = *(const f32x4*)(prior + c);
  }
  if (m == 1) {
    float r = rw[0];
    bf16x4 gv = *(const bf16x4*)(gen_t + idx);
#pragma unroll
    for (int k = 0; k < 4; ++k) ot[k] = r * tv[k] + (1.f - r) * (float)gv[k];
  } else if (m == 3) {
    ot = *(const f32x4*)(prior + 512 + c);
  }
  *(f32x4*)(out + idx) = oi;
  *(f32x4*)(out + (size_t)BDIM * HDIM + idx) = ot;
}

// ---------------------------------------------------------------- launch

extern "C" void kernel_launch(void* const* d_in, const int* in_sizes, int n_in,
                              void* d_out, int out_size, void* d_ws, size_t ws_size,
                              hipStream_t stream) {
  const float* img  = (const float*)d_in[0];
  const float* txt  = (const float*)d_in[1];
  const float* ipw  = (const float*)d_in[2];
  const float* ipb  = (const float*)d_in[3];
  const float* qkvw = (const float*)d_in[4];
  const float* qkvb = (const float*)d_in[5];
  const float* aow  = (const float*)d_in[6];
  const float* aob  = (const float*)d_in[7];
  const float* ln1g = (const float*)d_in[8];
  const float* ln1b = (const float*)d_in[9];
  const float* ln2g = (const float*)d_in[10];
  const float* ln2b = (const float*)d_in[11];
  const float* f1w  = (const float*)d_in[12];
  const float* f1b  = (const float*)d_in[13];
  const float* f2w  = (const float*)d_in[14];
  const float* f2b  = (const float*)d_in[15];
  const float* opw  = (const float*)d_in[16];
  const float* opb  = (const float*)d_in[17];
  const float* rw   = (const float*)d_in[18];
  const float* pw1  = (const float*)d_in[19];
  const float* pb1  = (const float*)d_in[20];
  const float* pw2  = (const float*)d_in[21];
  const float* pb2  = (const float*)d_in[22];
  const float* pemb = (const float*)d_in[23];
  const int*   mt   = (const int*)d_in[24];
  float* out = (float*)d_out;

  const size_t B = BDIM;
  char* ws = (char*)d_ws;
  size_t off = 0;
  auto alloc = [&](size_t bytes) -> char* {
    char* p = ws + off;
    off += (bytes + 255) & ~(size_t)255;
    return p;
  };
  bf16* src_bf = (bf16*)alloc(2 * B * 512 * 2);           // [0]=img, [1]=txt
  bf16* ipw_bf = (bf16*)alloc((size_t)2 * 262144 * 2);
  bf16* wvT_bf = (bf16*)alloc((size_t)6 * 262144 * 2);
  bf16* ao_bf  = (bf16*)alloc((size_t)6 * 262144 * 2);
  bf16* f1_bf  = (bf16*)alloc((size_t)6 * 1048576 * 2);
  bf16* f2_bf  = (bf16*)alloc((size_t)6 * 1048576 * 2);
  bf16* op_bf  = (bf16*)alloc((size_t)2 * 262144 * 2);
  bf16* Wc_bf  = (bf16*)alloc((size_t)6 * 262144 * 2);
  float* bc    = (float*)alloc(6 * 512 * 4);
  float* zeros = (float*)alloc(512 * 4);
  float* ph    = (float*)alloc(1024 * 4);
  float* pout  = (float*)alloc(1024 * 4);
  bf16* xn     = (bf16*)alloc(2 * B * 512 * 2);
  bf16* bufA   = (bf16*)alloc(2 * B * 512 * 2);
  bf16* bufB   = (bf16*)alloc(2 * B * 512 * 2);

  auto cvt = [&](const float* s, bf16* d, size_t n) {
    int n4 = (int)(n / 4);
    cvt_f32_bf16<<<(n4 + 255) / 256, 256, 0, stream>>>(s, d, n4);
  };
  cvt(img, src_bf, B * 512);
  cvt(txt, src_bf + B * 512, B * 512);
  cvt(ipw, ipw_bf, 2 * 262144);
  cvt(aow, ao_bf, 6 * 262144);
  cvt(f1w, f1_bf, 6 * 1048576);
  cvt(f2w, f2_bf, 6 * 1048576);
  cvt(opw, op_bf, 2 * 262144);
  cvt_wvT<<<dim3(16, 16, 6), 256, 0, stream>>>(qkvw, wvT_bf);
  zfill<<<2, 256, 0, stream>>>(zeros, 512);
  bias_combine<<<768, 256, 0, stream>>>(aow, qkvb, aob, bc);
  gemm128<<<dim3(4, 4, 6), 256, 0, stream>>>(ao_bf, 262144, 512, wvT_bf, 262144,
                                             zeros, 0, Wc_bf, 262144, 512, 512);
  prior_fc1<<<256, 256, 0, stream>>>(pemb, pw1, pb1, ph);
  prior_fc2<<<256, 256, 0, stream>>>(ph, pw2, pb2, pout);

  const long long BS = (long long)B * 512;

  // attn_l = tgt @ Wc_l^T + bc_l  (z=0 -> tgt=txt, z=1 -> tgt=img)
  auto attn = [&](int l, bf16* dst) {
    gemm_q<0, false, 512><<<dim3(128, 2, 2), 256, 0, stream>>>(
        src_bf + BS, -BS, Wc_bf + (size_t)l * 262144, 786432,
        bc + l * 512, 1536, nullptr, 0, dst, BS, 512);
  };
  attn(0, bufA);
  attn(1, bufB);

  // xn = src@ipw^T + ipb + attn0;  xn = LN1_0(xn)
  gemm_q<0, true, 512><<<dim3(128, 2, 2), 256, 0, stream>>>(
      src_bf, BS, ipw_bf, 262144, ipb, 512, bufA, BS, xn, BS, 512);
  ln_chain<0><<<2 * BDIM / 4, 256, 0, stream>>>(xn, nullptr, ln1g, ln1b,
                                                nullptr, nullptr, xn);
  attn(2, bufA);   // bufA free after ip consumed it

  for (int l = 0; l < 3; ++l) {
    // xn = xn + gelu(xn@f1^T + b1)@f2^T + b2   (fused, h in LDS only)
    gemm_mlp<<<dim3(256, 1, 2), 512, 0, stream>>>(
        xn, BS,
        f1_bf + (size_t)l * 1048576, 3145728,
        f1b + l * 2048, 6144,
        f2_bf + (size_t)l * 1048576, 3145728,
        f2b + l * 512, 1536,
        xn, BS);
    if (l < 2) {
      bf16* attnNext = (l == 0) ? bufB : bufA;
      // xn = LN1_{l+1}( LN2_l(xn) + attn_{l+1} )
      ln_chain<1><<<2 * BDIM / 4, 256, 0, stream>>>(
          xn, attnNext, ln2g + l * 512, ln2b + l * 512,
          ln1g + (l + 1) * 512, ln1b + (l + 1) * 512, xn);
    } else {
      // xn = LN2_2(xn)   (final x)
      ln_chain<0><<<2 * BDIM / 4, 256, 0, stream>>>(
          xn, nullptr, ln2g + l * 512, ln2b + l * 512, nullptr, nullptr, xn);
    }
  }

  // gen = xn @ opw^T + opb  (z=0 -> gen_text, z=1 -> gen_img) -> bufB
  gemm_q<0, false, 512><<<dim3(128, 2, 2), 256, 0, stream>>>(
      xn, BS, op_bf, 262144, opb, 512, nullptr, 0, bufB, BS, 512);

  combine<<<(BDIM * 128 + 255) / 256, 256, 0, stream>>>(img, txt, bufB, bufB + BS,
                                                        pout, mt, rw, out);
}

// Round 10
// 867.303 us; speedup vs baseline: 1.2876x; 1.2876x over previous
//
#include <hip/hip_runtime.h>
#include <hip/hip_bf16.h>
#include <math.h>

#define BDIM 16384
#define HDIM 512

typedef __bf16 bf16;
typedef float f32x4 __attribute__((ext_vector_type(4)));
typedef __bf16 bf16x8 __attribute__((ext_vector_type(8)));
typedef __bf16 bf16x4 __attribute__((ext_vector_type(4)));

#define WAITV(N) asm volatile("s_waitcnt vmcnt(" #N ")" ::: "memory")

// ---------------------------------------------------------------- utilities

__device__ __forceinline__ void gload16(const bf16* g, bf16* l) {
  __builtin_amdgcn_global_load_lds((const __attribute__((address_space(1))) void*)g,
                                   (__attribute__((address_space(3))) void*)l, 16, 0, 0);
}

__device__ __forceinline__ float gelu_exact(float x) {
  return 0.5f * x * (1.0f + erff(x * 0.70710678118654752f));
}
// gelu(x) ~= x * sigmoid(1.5957692*(x + 0.044715 x^3)); exp2-form, fast rcp.
__device__ __forceinline__ float gelu_fast2(float x) {
  float x3 = x * x * x;
  float e = exp2f(fmaf(-0.1029432f, x3, -2.3022082f * x));
  return x * __builtin_amdgcn_rcpf(1.f + e);
}

// ---------------------------------------------------------------- converts

__global__ void cvt_f32_bf16(const float* __restrict__ src, bf16* __restrict__ dst, int n4) {
  int i = blockIdx.x * blockDim.x + threadIdx.x;
  if (i >= n4) return;
  f32x4 v = *(const f32x4*)(src + (size_t)i * 4);
  bf16x4 o;
  o[0] = (bf16)v[0]; o[1] = (bf16)v[1]; o[2] = (bf16)v[2]; o[3] = (bf16)v[3];
  *(bf16x4*)(dst + (size_t)i * 4) = o;
}

// wvT[il][k][m] = wv[il][m][k]; wv = rows 1024..1535 of qkv block il ([1536][512])
__global__ void cvt_wvT(const float* __restrict__ qkv, bf16* __restrict__ dst) {
  __shared__ float t[32][33];
  int il = blockIdx.z;
  int bm = blockIdx.x * 32;
  int bk = blockIdx.y * 32;
  const float* s = qkv + (size_t)il * 786432 + 524288;
  int tx = threadIdx.x & 31, ty = threadIdx.x >> 5;
#pragma unroll
  for (int j = 0; j < 4; ++j)
    t[ty * 4 + j][tx] = s[(size_t)(bm + ty * 4 + j) * 512 + bk + tx];
  __syncthreads();
  bf16* d = dst + (size_t)il * 262144;
#pragma unroll
  for (int j = 0; j < 4; ++j)
    d[(size_t)(bk + ty * 4 + j) * 512 + bm + tx] = (bf16)t[tx][ty * 4 + j];
}

__global__ void zfill(float* __restrict__ p, int n) {
  int i = blockIdx.x * 256 + threadIdx.x;
  if (i < n) p[i] = 0.f;
}

// bc[il][n] = sum_m ao[il][n][m] * bv[il][m] + aob[il][n]
__global__ void bias_combine(const float* __restrict__ aow, const float* __restrict__ qkvb,
                             const float* __restrict__ aob, float* __restrict__ bc) {
  int gid = blockIdx.x * 4 + (threadIdx.x >> 6);
  int il = gid >> 9;
  int lane = threadIdx.x & 63;
  const float* ar = aow + (size_t)gid * 512 + lane * 8;
  const float* bv = qkvb + il * 1536 + 1024 + lane * 8;
  float s = 0.f;
#pragma unroll
  for (int i = 0; i < 8; ++i) s += ar[i] * bv[i];
#pragma unroll
  for (int off = 32; off > 0; off >>= 1) s += __shfl_xor(s, off);
  if (lane == 0) bc[gid] = s + aob[gid];
}

// ---------------------------------------------------------------- gemm_q
// 128x256 tile, BK=32, 4 waves (1Mx4N), 3-slot ring 72KiB -> 2 blocks/CU.
// 2-barrier kstep: stage all 6 units of tile t+2, counted vmcnt(12),
// barrier, 12 ds_reads, one 32-MFMA setprio cluster, barrier.
// Swapped mfma(b,a): row=m*16+lr, cols=bcol+wn+n*16+kg*4 (bf16x4 stores).
// z-batched via signed element strides (works across unrelated buffers).

template<int ACT, bool RES, int K>
__launch_bounds__(256, 2)
__global__ void gemm_q(const bf16* __restrict__ A, long long Az,
                       const bf16* __restrict__ W, long long Wz,
                       const float* __restrict__ bias, long long bz,
                       const bf16* X, long long Xz,
                       bf16* C, long long Cz, int ldc) {
  __shared__ bf16 lds[3][12288];   // slot: A[128][32] @0, B[256][32] @4096
  const long long z = blockIdx.z;
  A += z * Az; W += z * Wz; bias += z * bz; C += z * Cz;
  if (RES) X += z * Xz;
  const int tid = threadIdx.x, lane = tid & 63, wid = tid >> 6;
  const int brow = blockIdx.x * 128, bcol = blockIdx.y * 256;
  const int wn = wid * 64, lr = lane & 15, kg = lane >> 4;
  const int ko = (kg ^ ((lr >> 1) & 3)) << 3;

  f32x4 acc[8][4] = {};

  // staging: unit = 256 thr x 16B = 64 rows x 32 cols; src slot pre-inverse-swizzled
  const int sco = (((tid & 3) ^ ((tid >> 3) & 3)) << 3);
  const bf16* Ag = A + (size_t)(brow + (tid >> 2)) * K + sco;
  const bf16* Wg = W + (size_t)(bcol + (tid >> 2)) * K + sco;
  auto STAGE = [&](int s, int kt) {
#pragma unroll
    for (int u = 0; u < 2; ++u)
      gload16(Ag + (size_t)u * 64 * K + kt * 32, &lds[s][u * 2048 + wid * 512]);
#pragma unroll
    for (int u = 0; u < 4; ++u)
      gload16(Wg + (size_t)u * 64 * K + kt * 32, &lds[s][4096 + u * 2048 + wid * 512]);
  };

  const int nt = K / 32;
  STAGE(0, 0);
  STAGE(1, 1);

  int slot = 0;
  for (int t = 0; t < nt; ++t) {
    int s2 = slot + 2; if (s2 >= 3) s2 -= 3;
    const bf16* LA = &lds[slot][0];
    const bf16* LB = &lds[slot][4096];
    if (t + 2 < nt) { STAGE(s2, t + 2); WAITV(12); }
    else if (t + 1 < nt) WAITV(6);
    else WAITV(0);
    __builtin_amdgcn_s_barrier();
    bf16x8 a[8], b[4];
#pragma unroll
    for (int m = 0; m < 8; ++m) a[m] = *(const bf16x8*)(LA + ((m * 16 + lr) << 5) + ko);
#pragma unroll
    for (int n = 0; n < 4; ++n) b[n] = *(const bf16x8*)(LB + ((wn + n * 16 + lr) << 5) + ko);
    __builtin_amdgcn_s_setprio(1);
#pragma unroll
    for (int m = 0; m < 8; ++m)
#pragma unroll
      for (int n = 0; n < 4; ++n)
        acc[m][n] = __builtin_amdgcn_mfma_f32_16x16x32_bf16(b[n], a[m], acc[m][n], 0, 0, 0);
    __builtin_amdgcn_s_setprio(0);
    asm volatile("" ::: "memory");
    __builtin_amdgcn_s_barrier();
    slot += 1; if (slot >= 3) slot = 0;
  }

  // epilogue (swapped D): row = brow + m*16 + lr; cols = bcol+wn+n*16+kg*4 .. +3
  f32x4 bv4[4];
#pragma unroll
  for (int n = 0; n < 4; ++n)
    bv4[n] = *(const f32x4*)(bias + bcol + wn + n * 16 + kg * 4);
#pragma unroll
  for (int m = 0; m < 8; ++m) {
    int row = brow + m * 16 + lr;
#pragma unroll
    for (int n = 0; n < 4; ++n) {
      int col = bcol + wn + n * 16 + kg * 4;
      f32x4 v;
#pragma unroll
      for (int j = 0; j < 4; ++j) {
        float t = acc[m][n][j] + bv4[n][j];
        if (ACT == 1) t = gelu_fast2(t);
        v[j] = t;
      }
      if (RES) {
        bf16x4 xv = *(const bf16x4*)(X + (size_t)row * 512 + col);
#pragma unroll
        for (int j = 0; j < 4; ++j) v[j] += (float)xv[j];
      }
      bf16x4 o;
#pragma unroll
      for (int j = 0; j < 4; ++j) o[j] = (bf16)v[j];
      *(bf16x4*)(C + (size_t)row * ldc + col) = o;
    }
  }
}

// ---------------------------------------------------------------- ln_chain
// MODE 0: O = LN_A(Y);  MODE 1: O = LN_B( LN_A(Y) + R )
// rows of 512, one wave/row; gen = row>>14; LN params gen-stride 1536.

template<int MODE>
__global__ void ln_chain(const bf16* __restrict__ Y, const bf16* __restrict__ R,
                         const float* __restrict__ gA, const float* __restrict__ bA,
                         const float* __restrict__ gB, const float* __restrict__ bB,
                         bf16* __restrict__ O) {
  int lane = threadIdx.x & 63;
  int row = blockIdx.x * 4 + (threadIdx.x >> 6);
  int gen = row >> 14;
  size_t base = (size_t)row * HDIM + lane * 8;
  bf16x8 yv = *(const bf16x8*)(Y + base);
  float v[8], s = 0.f, q = 0.f;
#pragma unroll
  for (int i = 0; i < 8; ++i) { v[i] = (float)yv[i]; s += v[i]; q += v[i] * v[i]; }
#pragma unroll
  for (int off = 32; off > 0; off >>= 1) { s += __shfl_xor(s, off); q += __shfl_xor(q, off); }
  float mean = s * (1.f / HDIM);
  float rstd = rsqrtf(q * (1.f / HDIM) - mean * mean + 1e-5f);
  const float* gAp = gA + gen * 1536 + lane * 8;
  const float* bAp = bA + gen * 1536 + lane * 8;
  if (MODE == 0) {
    bf16x8 o;
#pragma unroll
    for (int i = 0; i < 8; ++i) o[i] = (bf16)((v[i] - mean) * rstd * gAp[i] + bAp[i]);
    *(bf16x8*)(O + base) = o;
    return;
  }
  bf16x8 rv = *(const bf16x8*)(R + base);
  float u[8]; s = 0.f; q = 0.f;
#pragma unroll
  for (int i = 0; i < 8; ++i) {
    u[i] = (v[i] - mean) * rstd * gAp[i] + bAp[i] + (float)rv[i];
    s += u[i]; q += u[i] * u[i];
  }
#pragma unroll
  for (int off = 32; off > 0; off >>= 1) { s += __shfl_xor(s, off); q += __shfl_xor(q, off); }
  float m2 = s * (1.f / HDIM);
  float r2 = rsqrtf(q * (1.f / HDIM) - m2 * m2 + 1e-5f);
  const float* gBp = gB + gen * 1536 + lane * 8;
  const float* bBp = bB + gen * 1536 + lane * 8;
  bf16x8 o;
#pragma unroll
  for (int i = 0; i < 8; ++i) o[i] = (bf16)((u[i] - m2) * r2 * gBp[i] + bBp[i]);
  *(bf16x8*)(O + base) = o;
}

// ---------------------------------------------------------------- GEMM 128x128 (tiny: Wc)

__launch_bounds__(256)
__global__ void gemm128(const bf16* __restrict__ A, long long Az, int lda,
                        const bf16* __restrict__ W, long long Wz,
                        const float* __restrict__ bias, long long bz,
                        bf16* __restrict__ C, long long Cz, int ldc, int K) {
  __shared__ bf16 As[128 * 64];
  __shared__ bf16 Bs[128 * 64];
  const long long z = blockIdx.z;
  A += z * Az; W += z * Wz; bias += z * bz; C += z * Cz;
  const int tid = threadIdx.x;
  const int lane = tid & 63;
  const int wid = tid >> 6;
  const int brow = blockIdx.x * 128;
  const int bcol = blockIdx.y * 128;
  const int wr = (wid >> 1) * 64;
  const int wc = (wid & 1) * 64;
  const int lr = lane & 15;
  const int kg = lane >> 4;
  f32x4 acc[4][4] = {};
  const bf16* Abase = A + (size_t)(brow + (tid >> 3)) * lda + ((tid & 7) << 3);
  const bf16* Wbase = W + (size_t)(bcol + (tid >> 3)) * K + ((tid & 7) << 3);
  bf16* AsDst = As + wid * 512;
  bf16* BsDst = Bs + wid * 512;
  for (int k0 = 0; k0 < K; k0 += 64) {
#pragma unroll
    for (int j = 0; j < 4; ++j) {
      gload16(Abase + (size_t)j * 32 * lda + k0, AsDst + j * 2048);
      gload16(Wbase + (size_t)j * 32 * K + k0, BsDst + j * 2048);
    }
    __syncthreads();
#pragma unroll
    for (int kk = 0; kk < 64; kk += 32) {
      bf16x8 a[4], bq[4];
#pragma unroll
      for (int m = 0; m < 4; ++m)
        a[m] = *(const bf16x8*)(As + (wr + m * 16 + lr) * 64 + kk + kg * 8);
#pragma unroll
      for (int n = 0; n < 4; ++n)
        bq[n] = *(const bf16x8*)(Bs + (wc + n * 16 + lr) * 64 + kk + kg * 8);
#pragma unroll
      for (int m = 0; m < 4; ++m)
#pragma unroll
        for (int n = 0; n < 4; ++n)
          acc[m][n] = __builtin_amdgcn_mfma_f32_16x16x32_bf16(a[m], bq[n], acc[m][n], 0, 0, 0);
    }
    __syncthreads();
  }
  float bv[4];
#pragma unroll
  for (int n = 0; n < 4; ++n) bv[n] = bias[bcol + wc + n * 16 + lr];
#pragma unroll
  for (int m = 0; m < 4; ++m) {
    int row = brow + wr + m * 16 + kg * 4;
#pragma unroll
    for (int n = 0; n < 4; ++n) {
      int col = bcol + wc + n * 16 + lr;
#pragma unroll
      for (int j = 0; j < 4; ++j)
        C[(size_t)(row + j) * ldc + col] = (bf16)(acc[m][n][j] + bv[n]);
    }
  }
}

// ---------------------------------------------------------------- prior MLP (tiny)

__global__ void prior_fc1(const float* __restrict__ emb, const float* __restrict__ w1,
                          const float* __restrict__ b1, float* __restrict__ h) {
  int j = blockIdx.x * 4 + (threadIdx.x >> 6);
  int lane = threadIdx.x & 63;
  const float* wr = w1 + (size_t)j * 512 + lane * 8;
  const float* e = emb + lane * 8;
  float s = 0.f;
#pragma unroll
  for (int i = 0; i < 8; ++i) s += e[i] * wr[i];
#pragma unroll
  for (int off = 32; off > 0; off >>= 1) s += __shfl_xor(s, off);
  if (lane == 0) h[j] = gelu_exact(s + b1[j]);
}

__global__ void prior_fc2(const float* __restrict__ h, const float* __restrict__ w2,
                          const float* __restrict__ b2, float* __restrict__ p) {
  int j = blockIdx.x * 4 + (threadIdx.x >> 6);
  int lane = threadIdx.x & 63;
  const float* wr = w2 + (size_t)j * 1024 + lane * 16;
  const float* e = h + lane * 16;
  float s = 0.f;
#pragma unroll
  for (int i = 0; i < 16; ++i) s += e[i] * wr[i];
#pragma unroll
  for (int off = 32; off > 0; off >>= 1) s += __shfl_xor(s, off);
  if (lane == 0) p[j] = s + b2[j];
}

// ---------------------------------------------------------------- final select/blend

__global__ void combine(const float* __restrict__ img, const float* __restrict__ txt,
                        const bf16* __restrict__ gen_t, const bf16* __restrict__ gen_i,
                        const float* __restrict__ prior, const int* __restrict__ mt,
                        const float* __restrict__ rw, float* __restrict__ out) {
  int i4 = blockIdx.x * blockDim.x + threadIdx.x;
  if (i4 >= BDIM * 128) return;
  int bb = i4 >> 7;
  int c = (i4 & 127) << 2;
  size_t idx = (size_t)bb * HDIM + c;
  int m = mt[bb];
  f32x4 iv = *(const f32x4*)(img + idx);
  f32x4 tv = *(const f32x4*)(txt + idx);
  f32x4 oi = iv, ot = tv;
  if (m == 2) {
    float r = rw[1];
    bf16x4 gv = *(const bf16x4*)(gen_i + idx);
#pragma unroll
    for (int k = 0; k < 4; ++k) oi[k] = r * iv[k] + (1.f - r) * (float)gv[k];
  } else if (m == 3) {
    oi = *(const f32x4*)(prior + c);
  }
  if (m == 1) {
    float r = rw[0];
    bf16x4 gv = *(const bf16x4*)(gen_t + idx);
#pragma unroll
    for (int k = 0; k < 4; ++k) ot[k] = r * tv[k] + (1.f - r) * (float)gv[k];
  } else if (m == 3) {
    ot = *(const f32x4*)(prior + 512 + c);
  }
  *(f32x4*)(out + idx) = oi;
  *(f32x4*)(out + (size_t)BDIM * HDIM + idx) = ot;
}

// ---------------------------------------------------------------- launch

extern "C" void kernel_launch(void* const* d_in, const int* in_sizes, int n_in,
                              void* d_out, int out_size, void* d_ws, size_t ws_size,
                              hipStream_t stream) {
  const float* img  = (const float*)d_in[0];
  const float* txt  = (const float*)d_in[1];
  const float* ipw  = (const float*)d_in[2];
  const float* ipb  = (const float*)d_in[3];
  const float* qkvw = (const float*)d_in[4];
  const float* qkvb = (const float*)d_in[5];
  const float* aow  = (const float*)d_in[6];
  const float* aob  = (const float*)d_in[7];
  const float* ln1g = (const float*)d_in[8];
  const float* ln1b = (const float*)d_in[9];
  const float* ln2g = (const float*)d_in[10];
  const float* ln2b = (const float*)d_in[11];
  const float* f1w  = (const float*)d_in[12];
  const float* f1b  = (const float*)d_in[13];
  const float* f2w  = (const float*)d_in[14];
  const float* f2b  = (const float*)d_in[15];
  const float* opw  = (const float*)d_in[16];
  const float* opb  = (const float*)d_in[17];
  const float* rw   = (const float*)d_in[18];
  const float* pw1  = (const float*)d_in[19];
  const float* pb1  = (const float*)d_in[20];
  const float* pw2  = (const float*)d_in[21];
  const float* pb2  = (const float*)d_in[22];
  const float* pemb = (const float*)d_in[23];
  const int*   mt   = (const int*)d_in[24];
  float* out = (float*)d_out;

  const size_t B = BDIM;
  char* ws = (char*)d_ws;
  size_t off = 0;
  auto alloc = [&](size_t bytes) -> char* {
    char* p = ws + off;
    off += (bytes + 255) & ~(size_t)255;
    return p;
  };
  bf16* src_bf = (bf16*)alloc(2 * B * 512 * 2);           // [0]=img, [1]=txt
  bf16* ipw_bf = (bf16*)alloc((size_t)2 * 262144 * 2);
  bf16* wvT_bf = (bf16*)alloc((size_t)6 * 262144 * 2);
  bf16* ao_bf  = (bf16*)alloc((size_t)6 * 262144 * 2);
  bf16* f1_bf  = (bf16*)alloc((size_t)6 * 1048576 * 2);
  bf16* f2_bf  = (bf16*)alloc((size_t)6 * 1048576 * 2);
  bf16* op_bf  = (bf16*)alloc((size_t)2 * 262144 * 2);
  bf16* Wc_bf  = (bf16*)alloc((size_t)6 * 262144 * 2);
  float* bc    = (float*)alloc(6 * 512 * 4);
  float* zeros = (float*)alloc(512 * 4);
  float* ph    = (float*)alloc(1024 * 4);
  float* pout  = (float*)alloc(1024 * 4);
  bf16* xn     = (bf16*)alloc(2 * B * 512 * 2);
  bf16* hreg   = (bf16*)alloc((size_t)B * 2048 * 2);   // 64 MB: gen1 h / attn buf / gen buf
  bf16* h0     = (bf16*)d_out;                          // 64 MB: gen0 h (dead before combine)
  const long long HZ = (long long)(hreg - h0);          // z-stride h0 -> h1

  auto cvt = [&](const float* s, bf16* d, size_t n) {
    int n4 = (int)(n / 4);
    cvt_f32_bf16<<<(n4 + 255) / 256, 256, 0, stream>>>(s, d, n4);
  };
  cvt(img, src_bf, B * 512);
  cvt(txt, src_bf + B * 512, B * 512);
  cvt(ipw, ipw_bf, 2 * 262144);
  cvt(aow, ao_bf, 6 * 262144);
  cvt(f1w, f1_bf, 6 * 1048576);
  cvt(f2w, f2_bf, 6 * 1048576);
  cvt(opw, op_bf, 2 * 262144);
  cvt_wvT<<<dim3(16, 16, 6), 256, 0, stream>>>(qkvw, wvT_bf);
  zfill<<<2, 256, 0, stream>>>(zeros, 512);
  bias_combine<<<768, 256, 0, stream>>>(aow, qkvb, aob, bc);
  gemm128<<<dim3(4, 4, 6), 256, 0, stream>>>(ao_bf, 262144, 512, wvT_bf, 262144,
                                             zeros, 0, Wc_bf, 262144, 512, 512);
  prior_fc1<<<256, 256, 0, stream>>>(pemb, pw1, pb1, ph);
  prior_fc2<<<256, 256, 0, stream>>>(ph, pw2, pb2, pout);

  const long long BS = (long long)B * 512;

  // attn_l -> hreg (z=0) / hreg+BS (z=1); tgt: z=0 -> txt, z=1 -> img
  auto attn = [&](int l) {
    gemm_q<0, false, 512><<<dim3(128, 2, 2), 256, 0, stream>>>(
        src_bf + BS, -BS, Wc_bf + (size_t)l * 262144, 786432,
        bc + l * 512, 1536, nullptr, 0, hreg, BS, 512);
  };

  // xn = src@ipw^T + ipb + attn0;  xn = LN1_0(xn)
  attn(0);
  gemm_q<0, true, 512><<<dim3(128, 2, 2), 256, 0, stream>>>(
      src_bf, BS, ipw_bf, 262144, ipb, 512, hreg, BS, xn, BS, 512);
  ln_chain<0><<<2 * BDIM / 4, 256, 0, stream>>>(xn, nullptr, ln1g, ln1b,
                                                nullptr, nullptr, xn);

  for (int l = 0; l < 3; ++l) {
    // h = gelu(xn @ f1^T + b1)   (z-batched: gen0 h in d_out, gen1 h in hreg)
    gemm_q<1, false, 512><<<dim3(128, 8, 2), 256, 0, stream>>>(
        xn, BS, f1_bf + (size_t)l * 1048576, 3145728,
        f1b + l * 2048, 6144, nullptr, 0, h0, HZ, 2048);
    // xn = xn + h @ f2^T + b2   (z-batched, in place)
    gemm_q<0, true, 2048><<<dim3(128, 2, 2), 256, 0, stream>>>(
        h0, HZ, f2_bf + (size_t)l * 1048576, 3145728,
        f2b + l * 512, 1536, xn, BS, xn, BS, 512);
    if (l < 2) {
      attn(l + 1);   // h dead now; hreg reused as attn buffer
      // xn = LN1_{l+1}( LN2_l(xn) + attn_{l+1} )
      ln_chain<1><<<2 * BDIM / 4, 256, 0, stream>>>(
          xn, hreg, ln2g + l * 512, ln2b + l * 512,
          ln1g + (l + 1) * 512, ln1b + (l + 1) * 512, xn);
    } else {
      // xn = LN2_2(xn)   (final x)
      ln_chain<0><<<2 * BDIM / 4, 256, 0, stream>>>(
          xn, nullptr, ln2g + l * 512, ln2b + l * 512, nullptr, nullptr, xn);
    }
  }

  // gen = xn @ opw^T + opb  (z=0 -> gen_text, z=1 -> gen_img) -> hreg
  gemm_q<0, false, 512><<<dim3(128, 2, 2), 256, 0, stream>>>(
      xn, BS, op_bf, 262144, opb, 512, nullptr, 0, hreg, BS, 512);

  combine<<<(BDIM * 128 + 255) / 256, 256, 0, stream>>>(img, txt, hreg, hreg + BS,
                                                        pout, mt, rw, out);
}